// Round 2
// baseline (143.787 us; speedup 1.0000x reference)
//
#include <hip/hip_runtime.h>
#include <float.h>

#define TT 200
#define DD 64
#define BLOCK 256
#define TB 64                      // T-tile rows
#define NT ((TT + TB - 1) / TB)    // 4 tiles: 64,64,64,8
#define KS 68                      // padded K row stride (floats)
#define NEG_INF_F (-4294967296.0f) // f32 rounding of -(2^32-1)

__global__ __launch_bounds__(BLOCK, 6) void attn_pool_kernel(
    const float* __restrict__ queries, const float* __restrict__ keys,
    const int* __restrict__ masks, const float* __restrict__ W1,
    const float* __restrict__ b1, const float* __restrict__ W2,
    const float* __restrict__ b2, const float* __restrict__ W3,
    const float* __restrict__ b3, float* __restrict__ out)
{
    __shared__ __align__(16) float lds_k[TB][KS];   // 17,408 B
    __shared__ __align__(16) float lds_wk[DD][16];  // folded W1: [d][0..7]=W1k, [8..15]=W1qk
    __shared__ __align__(16) float lds_q[DD];
    __shared__ float lds_qw1[8];
    __shared__ float lds_score[TB];
    __shared__ float red[4];
    __shared__ __align__(16) float lds_part[4][DD];
    __shared__ float s_tilemax, s_w2[32], s_w3[4], s_b2[4], s_b3;

    const int b = blockIdx.x;
    const int tid = threadIdx.x;
    const int wave = tid >> 6;
    const int lane = tid & 63;
    const int t_l = tid >> 2;   // score role: local t (0..63)
    const int p   = tid & 3;    // score role: d-chunk (16 d's each)

    // ---- per-block setup ----
    if (tid < DD) lds_q[tid] = queries[b * DD + tid];
    if (tid >= 64 && tid < 96)  s_w2[tid - 64] = W2[tid - 64];
    if (tid >= 96 && tid < 100) s_w3[tid - 96] = W3[tid - 96];
    if (tid >= 100 && tid < 104) s_b2[tid - 100] = b2[tid - 100];
    if (tid == 104) s_b3 = b3[0];
    // fold W1:  att_in@W1 = q@(W1a+W1c) + k@(W1b-W1c) + (q*k)@W1d
    for (int f = tid; f < DD * 16; f += BLOCK) {
        int d = f >> 4, s = f & 15;
        float v;
        if (s < 8) v = W1[(64 + d) * 8 + s] - W1[(128 + d) * 8 + s];
        else       v = W1[(192 + d) * 8 + (s - 8)];
        lds_wk[d][s] = v;
    }
    __syncthreads();
    // per-batch constant: qW1 = q@(W1a+W1c) + b1  (8 scalars)
    if (tid < 8) {
        float s = b1[tid];
        for (int d = 0; d < DD; ++d)
            s = fmaf(lds_q[d], W1[d * 8 + tid] + W1[(128 + d) * 8 + tid], s);
        lds_qw1[tid] = s;
    }

    // ---- online-softmax state (replicated per thread; identical values) ----
    float m_run = -FLT_MAX;   // running max
    float s_run = 0.0f;       // this wave's partial exp-sum (lane-replicated)
    float acc   = 0.0f;       // this wave's partial out[d], d = lane

    const float4* kbase = (const float4*)(keys + (size_t)b * TT * DD);
    const int* mrow = masks + (size_t)b * TT;

    for (int it = 0; it < NT; ++it) {
        const int rows = (it == NT - 1) ? (TT - (NT - 1) * TB) : TB;
        __syncthreads();                         // prev PV done with lds_k
        // ---- stage K tile (coalesced float4) ----
        for (int i = tid; i < rows * (DD / 4); i += BLOCK) {
            int row = i >> 4, col = (i & 15) << 2;
            *(float4*)&lds_k[row][col] = kbase[it * TB * (DD / 4) + i];
        }
        __syncthreads();

        // ---- score: 4 threads per t, 16 d's each ----
        float score = -FLT_MAX;
        if (t_l < rows) {
            float a8[8] = {0, 0, 0, 0, 0, 0, 0, 0};
            const int d0 = p * 16;
#pragma unroll
            for (int i = 0; i < 4; ++i) {
                float4 kv4 = *(const float4*)&lds_k[t_l][d0 + 4 * i];
                float4 q4  = *(const float4*)&lds_q[d0 + 4 * i];
#pragma unroll
                for (int dd = 0; dd < 4; ++dd) {
                    float kv = (&kv4.x)[dd];
                    float qk = kv * (&q4.x)[dd];
                    const float* wr = lds_wk[d0 + 4 * i + dd];
#pragma unroll
                    for (int j = 0; j < 8; ++j) {
                        a8[j] = fmaf(kv, wr[j], a8[j]);
                        a8[j] = fmaf(qk, wr[8 + j], a8[j]);
                    }
                }
            }
#pragma unroll
            for (int j = 0; j < 8; ++j) {        // reduce across the 4 p-lanes
                a8[j] += __shfl_xor(a8[j], 1, 64);
                a8[j] += __shfl_xor(a8[j], 2, 64);
            }
            float h1[8];
#pragma unroll
            for (int j = 0; j < 8; ++j)
                h1[j] = 1.0f / (1.0f + __expf(-(a8[j] + lds_qw1[j])));
            float h2[4];
#pragma unroll
            for (int c = 0; c < 4; ++c) {
                float s = s_b2[c];
#pragma unroll
                for (int j = 0; j < 8; ++j) s = fmaf(h1[j], s_w2[j * 4 + c], s);
                h2[c] = 1.0f / (1.0f + __expf(-s));
            }
            float s = s_b3;
#pragma unroll
            for (int c = 0; c < 4; ++c) s = fmaf(h2[c], s_w3[c], s);
            score = mrow[it * TB + t_l] ? s : NEG_INF_F;
            if (p == 0) lds_score[t_l] = score;
        }
        // ---- tile max (wave reduce, then cross-wave) ----
        float mx = score;
#pragma unroll
        for (int off = 32; off; off >>= 1) mx = fmaxf(mx, __shfl_xor(mx, off, 64));
        if (lane == 0) red[wave] = mx;
        __syncthreads();
        if (tid == 0)
            s_tilemax = fmaxf(fmaxf(red[0], red[1]), fmaxf(red[2], red[3]));
        __syncthreads();

        // ---- online update + PV accumulate (wave role: lane = d) ----
        const float m_new = fmaxf(m_run, s_tilemax);
        const float f = __expf(m_run - m_new);   // 0 when m_run = -FLT_MAX
        acc *= f;
        s_run *= f;
        m_run = m_new;
        for (int tl = wave; tl < rows; tl += 4) {
            float e = __expf(lds_score[tl] - m_new);
            acc = fmaf(e, lds_k[tl][lane], acc);
            s_run += e;
        }
    }

    // ---- combine waves, normalize, store ----
    lds_part[wave][lane] = acc;
    if (lane == 0) red[wave] = s_run;
    __syncthreads();
    if (tid < DD) {
        float tot = red[0] + red[1] + red[2] + red[3];
        float r = (lds_part[0][tid] + lds_part[1][tid] +
                   lds_part[2][tid] + lds_part[3][tid]) / tot;
        out[b * DD + tid] = r;
    }
}

extern "C" void kernel_launch(void* const* d_in, const int* in_sizes, int n_in,
                              void* d_out, int out_size, void* d_ws, size_t ws_size,
                              hipStream_t stream) {
    const float* queries = (const float*)d_in[0];
    const float* keys    = (const float*)d_in[1];
    const int*   masks   = (const int*)d_in[2];
    const float* W1      = (const float*)d_in[3];
    const float* b1      = (const float*)d_in[4];
    const float* W2      = (const float*)d_in[5];
    const float* b2      = (const float*)d_in[6];
    const float* W3      = (const float*)d_in[7];
    const float* b3      = (const float*)d_in[8];
    float* out = (float*)d_out;

    const int B = in_sizes[0] / DD;  // 4096
    attn_pool_kernel<<<B, BLOCK, 0, stream>>>(queries, keys, masks, W1, b1, W2, b2, W3, b3, out);
}

// Round 3
// 79.719 us; speedup vs baseline: 1.8037x; 1.8037x over previous
//
#include <hip/hip_runtime.h>

#define TT 200
#define DD 64
#define BLOCK 256
#define KSH 72   // bf16 halfwords per K row in LDS (144 B -> 16B-aligned rows, stride-1-like banks)

typedef unsigned short u16;
typedef unsigned int u32;
typedef __attribute__((ext_vector_type(8))) u16 ushort8;

__device__ __forceinline__ float bf2f(u16 h) {
    union { u32 u; float f; } v; v.u = ((u32)h) << 16; return v.f;
}
__device__ __forceinline__ u16 f2bf(float f) {
    union { float f; u32 u; } v; v.f = f;
    return (u16)((v.u + 0x7FFFu + ((v.u >> 16) & 1u)) >> 16);
}
__device__ __forceinline__ float sigmoid_fast(float x) {
    // 1/(1+exp(-x)); rcp is ~1ulp, fine for our 9e-3 budget
    return __builtin_amdgcn_rcpf(1.0f + __expf(-x));
}

__global__ __launch_bounds__(BLOCK, 5) void attn_pool_kernel(
    const float* __restrict__ queries, const float* __restrict__ keys,
    const int* __restrict__ masks, const float* __restrict__ W1,
    const float* __restrict__ b1, const float* __restrict__ W2,
    const float* __restrict__ b2, const float* __restrict__ W3,
    const float* __restrict__ b3, float* __restrict__ out)
{
    __shared__ __align__(16) u16   lds_kh[TT][KSH];   // 28,800 B (dead after score; part/red alias it)
    __shared__ __align__(16) float lds_cw[DD][8];     // 2,048 B  folded weights
    __shared__ __align__(16) float lds_q[DD];         // 256 B
    __shared__ float lds_qw1[8];                      // 32 B
    __shared__ float lds_e[TT];                       // 800 B
    float* part = (float*)&lds_kh[0][0];              // [4][64] aliased
    float* red  = part + 4 * DD;                      // [4]     aliased

    const int b = blockIdx.x;
    const int tid = threadIdx.x;
    const int wave = tid >> 6;
    const int lane = tid & 63;

    // ---------------- phase A: stage q, stage K (fp32->bf16), qw1 by wave 0 ----------------
    float qreg = 0.0f;
    if (tid < DD) { qreg = queries[b * DD + tid]; lds_q[tid] = qreg; }

    const float4* kp = (const float4*)(keys + (size_t)b * TT * DD);
#pragma unroll
    for (int i = tid; i < TT * DD / 8; i += BLOCK) {   // 1600 chunks of 8 floats, 7 iters
        float4 a = kp[2 * i], c = kp[2 * i + 1];
        int row = i >> 3, col = (i & 7) << 3;
        ushort8 w;
        w[0] = f2bf(a.x); w[1] = f2bf(a.y); w[2] = f2bf(a.z); w[3] = f2bf(a.w);
        w[4] = f2bf(c.x); w[5] = f2bf(c.y); w[6] = f2bf(c.z); w[7] = f2bf(c.w);
        *(ushort8*)&lds_kh[row][col] = w;
    }

    if (wave == 0) {
        // qw1[j] = b1[j] + sum_d q[d] * (W1a + W1c)[d][j]; lane = d
        const float4* wa = (const float4*)&W1[lane * 8];          // W1a row
        const float4* wc = (const float4*)&W1[(128 + lane) * 8];  // W1c row
        float4 a0 = wa[0], a1 = wa[1], c0 = wc[0], c1 = wc[1];
        float p8[8];
        p8[0] = qreg * (a0.x + c0.x); p8[1] = qreg * (a0.y + c0.y);
        p8[2] = qreg * (a0.z + c0.z); p8[3] = qreg * (a0.w + c0.w);
        p8[4] = qreg * (a1.x + c1.x); p8[5] = qreg * (a1.y + c1.y);
        p8[6] = qreg * (a1.z + c1.z); p8[7] = qreg * (a1.w + c1.w);
#pragma unroll
        for (int j = 0; j < 8; ++j) {
#pragma unroll
            for (int off = 32; off; off >>= 1)
                p8[j] += __shfl_xor(p8[j], off, 64);
        }
        if (lane == 0) {
#pragma unroll
            for (int j = 0; j < 8; ++j) lds_qw1[j] = p8[j] + b1[j];
        }
    }
    __syncthreads();

    // ---------------- phase B: folded weights cw[d][j] = (W1b-W1c)[d][j] + q[d]*W1d[d][j] ----
#pragma unroll
    for (int f = tid; f < DD * 8; f += BLOCK) {
        int d = f >> 3, j = f & 7;
        lds_cw[d][j] = W1[(64 + d) * 8 + j] - W1[(128 + d) * 8 + j]
                     + lds_q[d] * W1[(192 + d) * 8 + j];
    }
    __syncthreads();

    // ---------------- phase C: score, 2 rows per thread (t, t+100) ----------------
    if (tid < 100) {
        const int t0 = tid, t1 = tid + 100;
        float a8a[8] = {0, 0, 0, 0, 0, 0, 0, 0};
        float a8b[8] = {0, 0, 0, 0, 0, 0, 0, 0};
#pragma unroll
        for (int i8 = 0; i8 < 8; ++i8) {
            ushort8 ka = *(const ushort8*)&lds_kh[t0][i8 << 3];
            ushort8 kb = *(const ushort8*)&lds_kh[t1][i8 << 3];
#pragma unroll
            for (int dd = 0; dd < 8; ++dd) {
                const int d = (i8 << 3) + dd;
                float4 cw0 = *(const float4*)&lds_cw[d][0];   // broadcast (uniform addr)
                float4 cw1 = *(const float4*)&lds_cw[d][4];
                float va = bf2f(ka[dd]), vb = bf2f(kb[dd]);
                a8a[0] = fmaf(va, cw0.x, a8a[0]); a8b[0] = fmaf(vb, cw0.x, a8b[0]);
                a8a[1] = fmaf(va, cw0.y, a8a[1]); a8b[1] = fmaf(vb, cw0.y, a8b[1]);
                a8a[2] = fmaf(va, cw0.z, a8a[2]); a8b[2] = fmaf(vb, cw0.z, a8b[2]);
                a8a[3] = fmaf(va, cw0.w, a8a[3]); a8b[3] = fmaf(vb, cw0.w, a8b[3]);
                a8a[4] = fmaf(va, cw1.x, a8a[4]); a8b[4] = fmaf(vb, cw1.x, a8b[4]);
                a8a[5] = fmaf(va, cw1.y, a8a[5]); a8b[5] = fmaf(vb, cw1.y, a8b[5]);
                a8a[6] = fmaf(va, cw1.z, a8a[6]); a8b[6] = fmaf(vb, cw1.z, a8b[6]);
                a8a[7] = fmaf(va, cw1.w, a8a[7]); a8b[7] = fmaf(vb, cw1.w, a8b[7]);
            }
        }
        // MLP tail for both rows
        float h1a[8], h1b[8];
#pragma unroll
        for (int j = 0; j < 8; ++j) {
            h1a[j] = sigmoid_fast(a8a[j] + lds_qw1[j]);
            h1b[j] = sigmoid_fast(a8b[j] + lds_qw1[j]);
        }
        float sa = b3[0], sb = b3[0];
#pragma unroll
        for (int c = 0; c < 4; ++c) {
            float ha = b2[c], hb = b2[c];
#pragma unroll
            for (int j = 0; j < 8; ++j) {
                float w2 = W2[j * 4 + c];
                ha = fmaf(h1a[j], w2, ha);
                hb = fmaf(h1b[j], w2, hb);
            }
            float w3 = W3[c];
            sa = fmaf(sigmoid_fast(ha), w3, sa);
            sb = fmaf(sigmoid_fast(hb), w3, sb);
        }
        // no-max softmax: scores bounded (|s| <~ 0.5), masked -> 0
        lds_e[t0] = masks[b * TT + t0] ? __expf(sa) : 0.0f;
        lds_e[t1] = masks[b * TT + t1] ? __expf(sb) : 0.0f;
    }
    __syncthreads();

    // ---------------- phase D: PV from fp32 global (L1/L2-hot, coalesced) ----------------
    const float* krow = keys + (size_t)b * TT * DD;
    float acc = 0.0f, s_run = 0.0f;
#pragma unroll 5
    for (int t = wave; t < TT; t += 4) {   // 50 iters per wave
        float e = lds_e[t];
        acc = fmaf(e, krow[t * DD + lane], acc);
        s_run += e;
    }
    part[wave * DD + lane] = acc;
    if (lane == 0) red[wave] = s_run;
    __syncthreads();

    // ---------------- phase E: combine + store ----------------
    if (tid < DD) {
        float tot = red[0] + red[1] + red[2] + red[3];
        float r = (part[tid] + part[DD + tid] + part[2 * DD + tid] + part[3 * DD + tid]) / tot;
        out[b * DD + tid] = r;
    }
}

extern "C" void kernel_launch(void* const* d_in, const int* in_sizes, int n_in,
                              void* d_out, int out_size, void* d_ws, size_t ws_size,
                              hipStream_t stream) {
    const float* queries = (const float*)d_in[0];
    const float* keys    = (const float*)d_in[1];
    const int*   masks   = (const int*)d_in[2];
    const float* W1      = (const float*)d_in[3];
    const float* b1      = (const float*)d_in[4];
    const float* W2      = (const float*)d_in[5];
    const float* b2      = (const float*)d_in[6];
    const float* W3      = (const float*)d_in[7];
    const float* b3      = (const float*)d_in[8];
    float* out = (float*)d_out;

    const int B = in_sizes[0] / DD;  // 4096
    attn_pool_kernel<<<B, BLOCK, 0, stream>>>(queries, keys, masks, W1, b1, W2, b2, W3, b3, out);
}

// Round 4
// 59.328 us; speedup vs baseline: 2.4236x; 1.3437x over previous
//
#include <hip/hip_runtime.h>

#define TT 200
#define DD 64
#define BLOCK 256
#define KSH 72   // bf16 halfwords per K row in LDS (144 B = 16B-aligned, stride-distributed banks)

typedef unsigned short u16;
typedef unsigned int u32;
typedef __attribute__((ext_vector_type(8))) u16 ushort8;

__device__ __forceinline__ float bflo(u32 w) {
    union { u32 u; float f; } v; v.u = w << 16; return v.f;
}
__device__ __forceinline__ float bfhi(u32 w) {
    union { u32 u; float f; } v; v.u = w & 0xFFFF0000u; return v.f;
}
__device__ __forceinline__ float bf2f(u16 h) {
    union { u32 u; float f; } v; v.u = ((u32)h) << 16; return v.f;
}
__device__ __forceinline__ u32 cvt_pk_bf16(float lo, float hi) {
    u32 r;
    asm("v_cvt_pk_bf16_f32 %0, %1, %2" : "=v"(r) : "v"(lo), "v"(hi));
    return r;
}
__device__ __forceinline__ float sigmoid_fast(float x) {
    return __builtin_amdgcn_rcpf(1.0f + __expf(-x));
}

__global__ __launch_bounds__(BLOCK, 5) void attn_pool_kernel(
    const float* __restrict__ queries, const float* __restrict__ keys,
    const int* __restrict__ masks, const float* __restrict__ W1,
    const float* __restrict__ b1, const float* __restrict__ W2,
    const float* __restrict__ b2, const float* __restrict__ W3,
    const float* __restrict__ b3, float* __restrict__ out)
{
    __shared__ __align__(16) u16   lds_kh[TT][KSH];   // 28,800 B
    __shared__ __align__(16) float lds_cw[DD][8];     // 2,048 B; aliased as part[4][64] in PV
    __shared__ __align__(16) float lds_qw1[8];
    __shared__ __align__(16) float lds_e[TT];
    float* part = (float*)&lds_cw[0][0];              // [4][64] floats, alias (WAR across barrier)

    const int b = blockIdx.x;
    const int tid = threadIdx.x;
    const int wave = tid >> 6;
    const int lane = tid & 63;

    // ---- prefetch masks (overlaps staging) ----
    int m0 = 0, m1 = 0;
    if (tid < 100) {
        m0 = masks[b * TT + tid];
        m1 = masks[b * TT + tid + 100];
    }

    // ---- stage K: fp32 global -> bf16 LDS (single global read of keys) ----
    const float4* kp = (const float4*)(keys + (size_t)b * TT * DD);
#pragma unroll
    for (int k = 0; k < 13; ++k) {
        int i = tid + (k << 8);
        if (i < TT * DD / 4) {
            float4 v = kp[i];
            u32 r0 = cvt_pk_bf16(v.x, v.y);
            u32 r1 = cvt_pk_bf16(v.z, v.w);
            int row = i >> 4, col = (i & 15) << 2;
            uint2 wpack; wpack.x = r0; wpack.y = r1;
            *(uint2*)&lds_kh[row][col] = wpack;       // ds_write_b64
        }
    }

    // ---- fold weights: cw[d][j] = (W1b-W1c)[d][j] + q[d]*W1d[d][j]  (global reads only) ----
#pragma unroll
    for (int f = tid; f < DD * 8; f += BLOCK) {
        int d = f >> 3, j = f & 7;
        float qd = queries[b * DD + d];
        lds_cw[d][j] = W1[(64 + d) * 8 + j] - W1[(128 + d) * 8 + j]
                     + qd * W1[(192 + d) * 8 + j];
    }

    // ---- qw1[j] = b1[j] + sum_d q[d]*(W1a+W1c)[d][j]  (wave 0, shuffle reduce) ----
    if (wave == 0) {
        float qd = queries[b * DD + lane];
        const float4* wa = (const float4*)&W1[lane * 8];
        const float4* wc = (const float4*)&W1[(128 + lane) * 8];
        float4 a0 = wa[0], a1 = wa[1], c0 = wc[0], c1 = wc[1];
        float p8[8];
        p8[0] = qd * (a0.x + c0.x); p8[1] = qd * (a0.y + c0.y);
        p8[2] = qd * (a0.z + c0.z); p8[3] = qd * (a0.w + c0.w);
        p8[4] = qd * (a1.x + c1.x); p8[5] = qd * (a1.y + c1.y);
        p8[6] = qd * (a1.z + c1.z); p8[7] = qd * (a1.w + c1.w);
#pragma unroll
        for (int j = 0; j < 8; ++j) {
#pragma unroll
            for (int off = 32; off; off >>= 1)
                p8[j] += __shfl_xor(p8[j], off, 64);
        }
        if (lane == 0) {
#pragma unroll
            for (int j = 0; j < 8; ++j) lds_qw1[j] = p8[j] + b1[j];
        }
    }
    __syncthreads();   // barrier 1: kh, cw, qw1 ready

    // ---- score: threads 0..99, two rows each (t, t+100) ----
    if (tid < 100) {
        const int t0 = tid, t1 = tid + 100;
        float a8a[8] = {0, 0, 0, 0, 0, 0, 0, 0};
        float a8b[8] = {0, 0, 0, 0, 0, 0, 0, 0};
#pragma unroll
        for (int i8 = 0; i8 < 8; ++i8) {
            ushort8 ka = *(const ushort8*)&lds_kh[t0][i8 << 3];
            ushort8 kb = *(const ushort8*)&lds_kh[t1][i8 << 3];
#pragma unroll
            for (int dd = 0; dd < 8; ++dd) {
                const int d = (i8 << 3) + dd;
                float4 cw0 = *(const float4*)&lds_cw[d][0];   // broadcast
                float4 cw1 = *(const float4*)&lds_cw[d][4];
                float va = bf2f(ka[dd]), vb = bf2f(kb[dd]);
                a8a[0] = fmaf(va, cw0.x, a8a[0]); a8b[0] = fmaf(vb, cw0.x, a8b[0]);
                a8a[1] = fmaf(va, cw0.y, a8a[1]); a8b[1] = fmaf(vb, cw0.y, a8b[1]);
                a8a[2] = fmaf(va, cw0.z, a8a[2]); a8b[2] = fmaf(vb, cw0.z, a8b[2]);
                a8a[3] = fmaf(va, cw0.w, a8a[3]); a8b[3] = fmaf(vb, cw0.w, a8b[3]);
                a8a[4] = fmaf(va, cw1.x, a8a[4]); a8b[4] = fmaf(vb, cw1.x, a8b[4]);
                a8a[5] = fmaf(va, cw1.y, a8a[5]); a8b[5] = fmaf(vb, cw1.y, a8b[5]);
                a8a[6] = fmaf(va, cw1.z, a8a[6]); a8b[6] = fmaf(vb, cw1.z, a8b[6]);
                a8a[7] = fmaf(va, cw1.w, a8a[7]); a8b[7] = fmaf(vb, cw1.w, a8b[7]);
            }
        }
        float4 qwA = *(const float4*)&lds_qw1[0];
        float4 qwB = *(const float4*)&lds_qw1[4];
        float h1a[8], h1b[8];
        h1a[0] = sigmoid_fast(a8a[0] + qwA.x); h1b[0] = sigmoid_fast(a8b[0] + qwA.x);
        h1a[1] = sigmoid_fast(a8a[1] + qwA.y); h1b[1] = sigmoid_fast(a8b[1] + qwA.y);
        h1a[2] = sigmoid_fast(a8a[2] + qwA.z); h1b[2] = sigmoid_fast(a8b[2] + qwA.z);
        h1a[3] = sigmoid_fast(a8a[3] + qwA.w); h1b[3] = sigmoid_fast(a8b[3] + qwA.w);
        h1a[4] = sigmoid_fast(a8a[4] + qwB.x); h1b[4] = sigmoid_fast(a8b[4] + qwB.x);
        h1a[5] = sigmoid_fast(a8a[5] + qwB.y); h1b[5] = sigmoid_fast(a8b[5] + qwB.y);
        h1a[6] = sigmoid_fast(a8a[6] + qwB.z); h1b[6] = sigmoid_fast(a8b[6] + qwB.z);
        h1a[7] = sigmoid_fast(a8a[7] + qwB.w); h1b[7] = sigmoid_fast(a8b[7] + qwB.w);
        float sa = b3[0], sb = b3[0];
#pragma unroll
        for (int c = 0; c < 4; ++c) {
            float ha = b2[c], hb = b2[c];
#pragma unroll
            for (int j = 0; j < 8; ++j) {
                float w2 = W2[j * 4 + c];
                ha = fmaf(h1a[j], w2, ha);
                hb = fmaf(h1b[j], w2, hb);
            }
            float w3 = W3[c];
            sa = fmaf(sigmoid_fast(ha), w3, sa);
            sb = fmaf(sigmoid_fast(hb), w3, sb);
        }
        // no-max softmax: |score| bounded (<~0.5), masked -> exactly 0
        lds_e[t0] = m0 ? __expf(sa) : 0.0f;
        lds_e[t1] = m1 ? __expf(sb) : 0.0f;
    }
    __syncthreads();   // barrier 2: e ready; cw dead -> part alias live

    // ---- PV from bf16 LDS: lane = (half, d-pair); 8 t-phases x 25 iters ----
    const int half = lane >> 5;
    const int dp = lane & 31;
    const int d0 = dp << 1;
    const int tbase = (wave << 1) + half;   // 0..7
    float acc0 = 0.0f, acc1 = 0.0f;
#pragma unroll
    for (int i = 0; i < 25; ++i) {
        const int t = tbase + (i << 3);
        u32 kw = *(const u32*)&lds_kh[t][d0];   // 2 bf16, 2 lanes/bank (free)
        float e = lds_e[t];
        acc0 = fmaf(e, bflo(kw), acc0);
        acc1 = fmaf(e, bfhi(kw), acc1);
    }
    acc0 += __shfl_xor(acc0, 32, 64);
    acc1 += __shfl_xor(acc1, 32, 64);
    if (half == 0) {
        float2 wpack; wpack.x = acc0; wpack.y = acc1;
        *(float2*)&part[wave * DD + d0] = wpack;
    }
    __syncthreads();   // barrier 3: partials ready

    // ---- epilogue (wave 0): e-sum + combine + store ----
    if (wave == 0) {
        float s = lds_e[lane] + lds_e[64 + lane] + lds_e[128 + lane];
        if (lane < 8) s += lds_e[192 + lane];
#pragma unroll
        for (int off = 32; off; off >>= 1) s += __shfl_xor(s, off, 64);
        float r = part[lane] + part[DD + lane] + part[2 * DD + lane] + part[3 * DD + lane];
        out[b * DD + lane] = r / s;
    }
}

extern "C" void kernel_launch(void* const* d_in, const int* in_sizes, int n_in,
                              void* d_out, int out_size, void* d_ws, size_t ws_size,
                              hipStream_t stream) {
    const float* queries = (const float*)d_in[0];
    const float* keys    = (const float*)d_in[1];
    const int*   masks   = (const int*)d_in[2];
    const float* W1      = (const float*)d_in[3];
    const float* b1      = (const float*)d_in[4];
    const float* W2      = (const float*)d_in[5];
    const float* b2      = (const float*)d_in[6];
    const float* W3      = (const float*)d_in[7];
    const float* b3      = (const float*)d_in[8];
    float* out = (float*)d_out;

    const int B = in_sizes[0] / DD;  // 4096
    attn_pool_kernel<<<B, BLOCK, 0, stream>>>(queries, keys, masks, W1, b1, W2, b2, W3, b3, out);
}

// Round 5
// 51.357 us; speedup vs baseline: 2.7998x; 1.1552x over previous
//
#include <hip/hip_runtime.h>

#define TT 200
#define DD 64
#define BLOCK 256
#define KSH 72      // bf16 halfwords per K row (144 B, 16B-aligned rows)
#define NTILE 13    // ceil(200/16) row-tiles

typedef unsigned short u16;
typedef unsigned int u32;
typedef __attribute__((ext_vector_type(8))) u16 ushort8;
typedef __attribute__((ext_vector_type(8))) short short8v;  // MFMA bf16x8 frag
typedef __attribute__((ext_vector_type(4))) float f32x4;    // MFMA acc

__device__ __forceinline__ float bflo(u32 w) {
    union { u32 u; float f; } v; v.u = w << 16; return v.f;
}
__device__ __forceinline__ float bfhi(u32 w) {
    union { u32 u; float f; } v; v.u = w & 0xFFFF0000u; return v.f;
}
__device__ __forceinline__ u16 f2bf(float f) {
    union { float f; u32 u; } v; v.f = f;
    return (u16)((v.u + 0x7FFFu + ((v.u >> 16) & 1u)) >> 16);
}
__device__ __forceinline__ u32 cvt_pk_bf16(float lo, float hi) {
    u32 r;
    asm("v_cvt_pk_bf16_f32 %0, %1, %2" : "=v"(r) : "v"(lo), "v"(hi));
    return r;
}
__device__ __forceinline__ float sigmoid_fast(float x) {
    return __builtin_amdgcn_rcpf(1.0f + __expf(-x));
}

__global__ __launch_bounds__(BLOCK, 4) void attn_pool_kernel(
    const float* __restrict__ queries, const float* __restrict__ keys,
    const int* __restrict__ masks, const float* __restrict__ W1,
    const float* __restrict__ b1, const float* __restrict__ W2,
    const float* __restrict__ b2, const float* __restrict__ W3,
    const float* __restrict__ b3, float* __restrict__ out)
{
    __shared__ __align__(16) u16   lds_kh[NTILE * 16][KSH];  // 29,952 B (rows 200..207 garbage, never consumed)
    __shared__ __align__(16) u16   lds_cwt[16][KSH];         // 2,304 B  CW^T bf16: [j][d] (rows 8..15 garbage, cols 8..15 of D unread)
    __shared__ __align__(16) float lds_s[NTILE * 16][8];     // 6,656 B  scores fp32
    __shared__ __align__(16) float lds_qw1[8];
    __shared__ __align__(16) float lds_e[TT];
    float* part = (float*)&lds_cwt[0][0];                    // [4][64] f32 alias (cwt dead after GEMM)
    float* red  = part + 4 * DD;

    const int b = blockIdx.x;
    const int tid = threadIdx.x;
    const int wave = tid >> 6;
    const int lane = tid & 63;

    // ---- prefetch masks ----
    int m0 = 0, m1 = 0;
    if (tid < 100) {
        m0 = masks[b * TT + tid];
        m1 = masks[b * TT + tid + 100];
    }

    // ---- stage K: fp32 global -> bf16 LDS (keys read exactly once) ----
    const float4* kp = (const float4*)(keys + (size_t)b * TT * DD);
#pragma unroll
    for (int k = 0; k < 13; ++k) {
        int i = tid + (k << 8);
        if (i < TT * DD / 4) {
            float4 v = kp[i];
            u32 r0 = cvt_pk_bf16(v.x, v.y);
            u32 r1 = cvt_pk_bf16(v.z, v.w);
            int row = i >> 4, col = (i & 15) << 2;
            uint2 wpack; wpack.x = r0; wpack.y = r1;
            *(uint2*)&lds_kh[row][col] = wpack;
        }
    }

    // ---- fold weights -> CW^T bf16: cwt[j][d] = (W1b-W1c)[d][j] + q[d]*W1d[d][j] ----
#pragma unroll
    for (int f = tid; f < DD * 8; f += BLOCK) {
        int d = f & 63, j = f >> 6;
        float qd = queries[b * DD + d];
        float v = W1[(64 + d) * 8 + j] - W1[(128 + d) * 8 + j]
                + qd * W1[(192 + d) * 8 + j];
        lds_cwt[j][d] = f2bf(v);
    }

    // ---- qw1[j] = b1[j] + sum_d q[d]*(W1a+W1c)[d][j]  (wave 0) ----
    if (wave == 0) {
        float qd = queries[b * DD + lane];
        const float4* wa = (const float4*)&W1[lane * 8];
        const float4* wc = (const float4*)&W1[(128 + lane) * 8];
        float4 a0 = wa[0], a1 = wa[1], c0 = wc[0], c1 = wc[1];
        float p8[8];
        p8[0] = qd * (a0.x + c0.x); p8[1] = qd * (a0.y + c0.y);
        p8[2] = qd * (a0.z + c0.z); p8[3] = qd * (a0.w + c0.w);
        p8[4] = qd * (a1.x + c1.x); p8[5] = qd * (a1.y + c1.y);
        p8[6] = qd * (a1.z + c1.z); p8[7] = qd * (a1.w + c1.w);
#pragma unroll
        for (int j = 0; j < 8; ++j) {
#pragma unroll
            for (int off = 32; off; off >>= 1)
                p8[j] += __shfl_xor(p8[j], off, 64);
        }
        if (lane == 0) {
#pragma unroll
            for (int j = 0; j < 8; ++j) lds_qw1[j] = p8[j] + b1[j];
        }
    }
    __syncthreads();   // B1: kh, cwt, qw1 ready

    // ---- score GEMM via MFMA: S = K @ CW, tiles split across waves ----
    {
        const int r = lane & 15, g = lane >> 4;
        short8v bf0 = *(const short8v*)&lds_cwt[r][g * 8];        // B frag, k=0..31
        short8v bf1 = *(const short8v*)&lds_cwt[r][32 + g * 8];   // B frag, k=32..63
        for (int tile = wave; tile < NTILE; tile += 4) {
            const int t0 = tile << 4;
            short8v a0 = *(const short8v*)&lds_kh[t0 + r][g * 8];
            short8v a1 = *(const short8v*)&lds_kh[t0 + r][32 + g * 8];
            f32x4 acc = {0.0f, 0.0f, 0.0f, 0.0f};
            acc = __builtin_amdgcn_mfma_f32_16x16x32_bf16(a0, bf0, acc, 0, 0, 0);
            acc = __builtin_amdgcn_mfma_f32_16x16x32_bf16(a1, bf1, acc, 0, 0, 0);
            if (r < 8) {                       // D: col(j)=lane&15, row(t)=g*4+reg
                const int rr = t0 + (g << 2);
                lds_s[rr + 0][r] = acc[0];
                lds_s[rr + 1][r] = acc[1];
                lds_s[rr + 2][r] = acc[2];
                lds_s[rr + 3][r] = acc[3];
            }
        }
    }
    __syncthreads();   // B2: S ready

    // ---- MLP tail: threads 0..99, rows (t, t+100) ----
    if (tid < 100) {
        const int t0 = tid, t1 = tid + 100;
        float4 sa0 = *(const float4*)&lds_s[t0][0];
        float4 sa1 = *(const float4*)&lds_s[t0][4];
        float4 sb0 = *(const float4*)&lds_s[t1][0];
        float4 sb1 = *(const float4*)&lds_s[t1][4];
        float4 qwA = *(const float4*)&lds_qw1[0];
        float4 qwB = *(const float4*)&lds_qw1[4];
        float h1a[8], h1b[8];
        h1a[0] = sigmoid_fast(sa0.x + qwA.x); h1b[0] = sigmoid_fast(sb0.x + qwA.x);
        h1a[1] = sigmoid_fast(sa0.y + qwA.y); h1b[1] = sigmoid_fast(sb0.y + qwA.y);
        h1a[2] = sigmoid_fast(sa0.z + qwA.z); h1b[2] = sigmoid_fast(sb0.z + qwA.z);
        h1a[3] = sigmoid_fast(sa0.w + qwA.w); h1b[3] = sigmoid_fast(sb0.w + qwA.w);
        h1a[4] = sigmoid_fast(sa1.x + qwB.x); h1b[4] = sigmoid_fast(sb1.x + qwB.x);
        h1a[5] = sigmoid_fast(sa1.y + qwB.y); h1b[5] = sigmoid_fast(sb1.y + qwB.y);
        h1a[6] = sigmoid_fast(sa1.z + qwB.z); h1b[6] = sigmoid_fast(sb1.z + qwB.z);
        h1a[7] = sigmoid_fast(sa1.w + qwB.w); h1b[7] = sigmoid_fast(sb1.w + qwB.w);
        float sa = b3[0], sb = b3[0];
#pragma unroll
        for (int c = 0; c < 4; ++c) {
            float ha = b2[c], hb = b2[c];
#pragma unroll
            for (int j = 0; j < 8; ++j) {
                float w2 = W2[j * 4 + c];
                ha = fmaf(h1a[j], w2, ha);
                hb = fmaf(h1b[j], w2, hb);
            }
            float w3 = W3[c];
            sa = fmaf(sigmoid_fast(ha), w3, sa);
            sb = fmaf(sigmoid_fast(hb), w3, sb);
        }
        // no-max softmax: |score| bounded (<~0.5), masked -> exactly 0
        lds_e[t0] = m0 ? __expf(sa) : 0.0f;
        lds_e[t1] = m1 ? __expf(sb) : 0.0f;
    }
    __syncthreads();   // B3: e ready; cwt dead -> part alias live

    // ---- PV from bf16 LDS (R4-proven, 0 conflicts): lane = (half, d-pair) ----
    const int half = lane >> 5;
    const int dp = lane & 31;
    const int d0 = dp << 1;
    const int tbase = (wave << 1) + half;   // 0..7
    float acc0 = 0.0f, acc1 = 0.0f;
#pragma unroll
    for (int i = 0; i < 25; ++i) {
        const int t = tbase + (i << 3);
        u32 kw = *(const u32*)&lds_kh[t][d0];
        float e = lds_e[t];
        acc0 = fmaf(e, bflo(kw), acc0);
        acc1 = fmaf(e, bfhi(kw), acc1);
    }
    acc0 += __shfl_xor(acc0, 32, 64);
    acc1 += __shfl_xor(acc1, 32, 64);
    if (half == 0) {
        float2 wpack; wpack.x = acc0; wpack.y = acc1;
        *(float2*)&part[wave * DD + d0] = wpack;
    }
    __syncthreads();   // B4: partials ready

    // ---- epilogue (wave 0): e-sum + combine + store ----
    if (wave == 0) {
        float s = lds_e[lane] + lds_e[64 + lane] + lds_e[128 + lane];
        if (lane < 8) s += lds_e[192 + lane];
#pragma unroll
        for (int off = 32; off; off >>= 1) s += __shfl_xor(s, off, 64);
        float r = part[lane] + part[DD + lane] + part[2 * DD + lane] + part[3 * DD + lane];
        out[b * DD + lane] = r / s;
    }
}

extern "C" void kernel_launch(void* const* d_in, const int* in_sizes, int n_in,
                              void* d_out, int out_size, void* d_ws, size_t ws_size,
                              hipStream_t stream) {
    const float* queries = (const float*)d_in[0];
    const float* keys    = (const float*)d_in[1];
    const int*   masks   = (const int*)d_in[2];
    const float* W1      = (const float*)d_in[3];
    const float* b1      = (const float*)d_in[4];
    const float* W2      = (const float*)d_in[5];
    const float* b2      = (const float*)d_in[6];
    const float* W3      = (const float*)d_in[7];
    const float* b3      = (const float*)d_in[8];
    float* out = (float*)d_out;

    const int B = in_sizes[0] / DD;  // 4096
    attn_pool_kernel<<<B, BLOCK, 0, stream>>>(queries, keys, masks, W1, b1, W2, b2, W3, b3, out);
}